// Round 1
// baseline (552.627 us; speedup 1.0000x reference)
//
#include <hip/hip_runtime.h>

#define CCH 2048   // channels
#define SP  32     // spatial H*W
// N (queries) = 32, M (tracklets) = 16, d5 groups = 64

// ---------- K1: WvSum[j][c] = sum_m Wv[(m*64+j)*C + c]; bvSum[j] ----------
__global__ void k_wvsum(const float* __restrict__ Wv, const float* __restrict__ bv,
                        float* __restrict__ WvSum, float* __restrict__ bvSum) {
    int t = blockIdx.x * 256 + threadIdx.x;   // 131072 = 64*2048
    int j = t >> 11, c = t & 2047;
    float s = 0.f;
    #pragma unroll 8
    for (int m = 0; m < 32; ++m) s += Wv[(m * 64 + j) * CCH + c];
    WvSum[t] = s;
    if (t < 64) {
        float b = 0.f;
        for (int m = 0; m < 32; ++m) b += bv[m * 64 + t];
        bvSum[t] = b;
    }
}

// ---------- K2: Sv[q][j*32+s] = sum_c WvSum[j][c] * x[q][c][s] + bvSum[j] ----------
__global__ void k_sv(const float* __restrict__ x, const float* __restrict__ WvSum,
                     const float* __restrict__ bvSum, float* __restrict__ Sv) {
    int jb = blockIdx.x;   // 0..7
    int q  = blockIdx.y;   // 0..31
    int tid = threadIdx.x; // 256
    int s = tid & 31, ty = tid >> 5;       // ty in [0,8)
    int j = jb * 8 + ty;
    __shared__ float xs[64][32];
    __shared__ float wsh[8][65];
    float acc = 0.f;
    for (int c0 = 0; c0 < CCH; c0 += 64) {
        for (int idx = tid; idx < 2048; idx += 256)
            xs[idx >> 5][idx & 31] = x[q * 65536 + (c0 + (idx >> 5)) * 32 + (idx & 31)];
        for (int idx = tid; idx < 512; idx += 256)
            wsh[idx >> 6][idx & 63] = WvSum[(jb * 8 + (idx >> 6)) * CCH + c0 + (idx & 63)];
        __syncthreads();
        #pragma unroll
        for (int cc = 0; cc < 64; ++cc)
            acc += wsh[ty][cc] * xs[cc][s];
        __syncthreads();
    }
    Sv[q * CCH + j * 32 + s] = acc + bvSum[j];
}

// ---------- K3: T[q][o] = sum_d Wo[o][d] * Sv[q][d] + bo[o] ----------
__global__ void k_t(const float* __restrict__ Sv, const float* __restrict__ Wo,
                    const float* __restrict__ bo, float* __restrict__ Tm) {
    int ob = blockIdx.x;   // 0..255 (8 o each)
    int tid = threadIdx.x;
    int q = tid & 31, ty = tid >> 5;
    int o = ob * 8 + ty;
    __shared__ float svs[32][65];
    __shared__ float wos[8][65];
    float acc = 0.f;
    for (int d0 = 0; d0 < CCH; d0 += 64) {
        for (int idx = tid; idx < 2048; idx += 256)
            svs[idx >> 6][idx & 63] = Sv[(idx >> 6) * CCH + d0 + (idx & 63)];
        for (int idx = tid; idx < 512; idx += 256)
            wos[idx >> 6][idx & 63] = Wo[(ob * 8 + (idx >> 6)) * CCH + d0 + (idx & 63)];
        __syncthreads();
        #pragma unroll
        for (int dd = 0; dd < 64; ++dd)
            acc += wos[ty][dd] * svs[q][dd];
        __syncthreads();
    }
    Tm[q * CCH + o] = acc + bo[o];
}

// ---------- K4: h1 = LN1(16*T[q][c] + x[q][c][s]) ----------
__global__ void k_ln1(const float* __restrict__ Tm, const float* __restrict__ x,
                      const float* __restrict__ lnw, const float* __restrict__ lnb,
                      float* __restrict__ h1) {
    int q = blockIdx.x;
    int tid = threadIdx.x;   // 1024
    const float* xb = x + q * 65536;
    const float* Tb = Tm + q * CCH;
    float sum = 0.f, ssq = 0.f;
    for (int i = tid; i < 65536; i += 1024) {
        float v = 16.f * Tb[i >> 5] + xb[i];
        sum += v; ssq += v * v;
    }
    #pragma unroll
    for (int off = 32; off > 0; off >>= 1) {
        sum += __shfl_down(sum, off);
        ssq += __shfl_down(ssq, off);
    }
    __shared__ float rs[16], rq[16];
    __shared__ float smu, srstd;
    int wid = tid >> 6;
    if ((tid & 63) == 0) { rs[wid] = sum; rq[wid] = ssq; }
    __syncthreads();
    if (tid == 0) {
        float S = 0.f, Q = 0.f;
        for (int w = 0; w < 16; ++w) { S += rs[w]; Q += rq[w]; }
        float mu = S * (1.f / 65536.f);
        float var = Q * (1.f / 65536.f) - mu * mu;
        smu = mu; srstd = rsqrtf(var + 1e-5f);
    }
    __syncthreads();
    float mu = smu, rstd = srstd;
    for (int i = tid; i < 65536; i += 1024) {
        float v = 16.f * Tb[i >> 5] + xb[i];
        h1[q * 65536 + i] = (v - mu) * rstd * lnw[i] + lnb[i];
    }
}

// ---------- GEMM: Out[q][o][s] = epi( sum_c A[o][c] * B[q][c][s] ) ----------
// MODE 0: relu -> Y1 ; MODE 1: + h1 -> out
template<int MODE>
__global__ void k_gemm(const float* __restrict__ A, const float* __restrict__ B,
                       const float* __restrict__ Badd, float* __restrict__ Out) {
    int q  = blockIdx.x;   // 32
    int ob = blockIdx.y;   // 16 (128 o-rows per block)
    int tid = threadIdx.x; // 256
    int s4 = tid & 7, og = tid >> 3;    // og in [0,32): 4 o rows each; s4: 4 s cols
    __shared__ float As[128][65];
    __shared__ __align__(16) float Bs[64][32];
    float acc[4][4] = {};
    const float* Bq = B + q * 65536;
    for (int c0 = 0; c0 < CCH; c0 += 64) {
        #pragma unroll
        for (int k = 0; k < 32; ++k) {
            int idx = tid + k * 256;
            As[idx >> 6][idx & 63] = A[(ob * 128 + (idx >> 6)) * CCH + c0 + (idx & 63)];
        }
        #pragma unroll
        for (int k = 0; k < 8; ++k) {
            int idx = tid + k * 256;
            Bs[idx >> 5][idx & 31] = Bq[(c0 + (idx >> 5)) * 32 + (idx & 31)];
        }
        __syncthreads();
        #pragma unroll
        for (int cc = 0; cc < 64; ++cc) {
            float4 b = *(const float4*)&Bs[cc][s4 * 4];
            float w0 = As[og * 4 + 0][cc];
            float w1 = As[og * 4 + 1][cc];
            float w2 = As[og * 4 + 2][cc];
            float w3 = As[og * 4 + 3][cc];
            acc[0][0] += w0 * b.x; acc[0][1] += w0 * b.y; acc[0][2] += w0 * b.z; acc[0][3] += w0 * b.w;
            acc[1][0] += w1 * b.x; acc[1][1] += w1 * b.y; acc[1][2] += w1 * b.z; acc[1][3] += w1 * b.w;
            acc[2][0] += w2 * b.x; acc[2][1] += w2 * b.y; acc[2][2] += w2 * b.z; acc[2][3] += w2 * b.w;
            acc[3][0] += w3 * b.x; acc[3][1] += w3 * b.y; acc[3][2] += w3 * b.z; acc[3][3] += w3 * b.w;
        }
        __syncthreads();
    }
    #pragma unroll
    for (int r = 0; r < 4; ++r) {
        int o = ob * 128 + og * 4 + r;
        long base = (long)q * 65536 + o * 32 + s4 * 4;
        float4 v;
        if (MODE == 0) {
            v.x = fmaxf(acc[r][0], 0.f); v.y = fmaxf(acc[r][1], 0.f);
            v.z = fmaxf(acc[r][2], 0.f); v.w = fmaxf(acc[r][3], 0.f);
        } else {
            float4 h = *(const float4*)&Badd[base];
            v.x = acc[r][0] + h.x; v.y = acc[r][1] + h.y;
            v.z = acc[r][2] + h.z; v.w = acc[r][3] + h.w;
        }
        *(float4*)&Out[base] = v;
    }
}

// ---------- K7: LN2 in-place on out ----------
__global__ void k_ln2(float* __restrict__ io, const float* __restrict__ lnw,
                      const float* __restrict__ lnb) {
    int q = blockIdx.x;
    int tid = threadIdx.x;   // 1024
    float* b = io + q * 65536;
    float sum = 0.f, ssq = 0.f;
    for (int i = tid; i < 65536; i += 1024) {
        float v = b[i]; sum += v; ssq += v * v;
    }
    #pragma unroll
    for (int off = 32; off > 0; off >>= 1) {
        sum += __shfl_down(sum, off);
        ssq += __shfl_down(ssq, off);
    }
    __shared__ float rs[16], rq[16];
    __shared__ float smu, srstd;
    int wid = tid >> 6;
    if ((tid & 63) == 0) { rs[wid] = sum; rq[wid] = ssq; }
    __syncthreads();
    if (tid == 0) {
        float S = 0.f, Q = 0.f;
        for (int w = 0; w < 16; ++w) { S += rs[w]; Q += rq[w]; }
        float mu = S * (1.f / 65536.f);
        float var = Q * (1.f / 65536.f) - mu * mu;
        smu = mu; srstd = rsqrtf(var + 1e-5f);
    }
    __syncthreads();
    float mu = smu, rstd = srstd;
    for (int i = tid; i < 65536; i += 1024) {
        float v = b[i];
        b[i] = (v - mu) * rstd * lnw[i] + lnb[i];
    }
}

extern "C" void kernel_launch(void* const* d_in, const int* in_sizes, int n_in,
                              void* d_out, int out_size, void* d_ws, size_t ws_size,
                              hipStream_t stream) {
    const float* x    = (const float*)d_in[0];
    // d_in[1..5] = x_g, Wq, bq, Wk, bk : dead code (softmax over singleton axis)
    const float* Wv   = (const float*)d_in[6];
    const float* bv   = (const float*)d_in[7];
    const float* Wo   = (const float*)d_in[8];
    const float* bo   = (const float*)d_in[9];
    const float* W1   = (const float*)d_in[10];
    const float* W2   = (const float*)d_in[11];
    const float* ln1w = (const float*)d_in[12];
    const float* ln1b = (const float*)d_in[13];
    const float* ln2w = (const float*)d_in[14];
    const float* ln2b = (const float*)d_in[15];
    float* out = (float*)d_out;

    float* ws    = (float*)d_ws;
    float* WvSum = ws;                 // 131072
    float* bvSum = ws + 131072;        // 64 (pad to 128)
    float* Sv    = ws + 131200;        // 65536
    float* Tm    = ws + 196736;        // 65536
    float* h1    = ws + 262272;        // 2097152
    float* Y1    = ws + 2359424;       // 2097152  -> total 4456576 floats (~17.8 MB)

    k_wvsum<<<512, 256, 0, stream>>>(Wv, bv, WvSum, bvSum);
    k_sv<<<dim3(8, 32), 256, 0, stream>>>(x, WvSum, bvSum, Sv);
    k_t<<<256, 256, 0, stream>>>(Sv, Wo, bo, Tm);
    k_ln1<<<32, 1024, 0, stream>>>(Tm, x, ln1w, ln1b, h1);
    k_gemm<0><<<dim3(32, 16), 256, 0, stream>>>(W1, h1, nullptr, Y1);
    k_gemm<1><<<dim3(32, 16), 256, 0, stream>>>(W2, Y1, h1, out);
    k_ln2<<<32, 1024, 0, stream>>>(out, ln2w, ln2b);
}

// Round 2
// 250.739 us; speedup vs baseline: 2.2040x; 2.2040x over previous
//
#include <hip/hip_runtime.h>

typedef unsigned short u16;
typedef __attribute__((ext_vector_type(8))) short bf16x8;
typedef __attribute__((ext_vector_type(4))) float f32x4;

#define CCH 2048

__device__ __forceinline__ u16 f2bf(float f) {
    unsigned int x = __float_as_uint(f);
    unsigned int r = (x + 0x7fffu + ((x >> 16) & 1u)) >> 16;
    return (u16)r;
}

__device__ __forceinline__ void gload_lds16(const u16* g, u16* l) {
    __builtin_amdgcn_global_load_lds((const __attribute__((address_space(1))) void*)g,
                                     (__attribute__((address_space(3))) void*)l, 16, 0, 0);
}

// ---------- convert W1,W2 fp32 -> bf16 ----------
__global__ void k_convert(const float* __restrict__ W1, const float* __restrict__ W2,
                          u16* __restrict__ W1b, u16* __restrict__ W2b) {
    int tg = blockIdx.x * 256 + threadIdx.x;      // 2097152 threads, 4 elems each
    long base = (long)tg * 4;
    const float* src; u16* dst; long off;
    if (base < 4194304) { src = W1; dst = W1b; off = base; }
    else                { src = W2; dst = W2b; off = base - 4194304; }
    float4 v = *(const float4*)&src[off];
    unsigned long long p = (unsigned long long)f2bf(v.x)
                         | ((unsigned long long)f2bf(v.y) << 16)
                         | ((unsigned long long)f2bf(v.z) << 32)
                         | ((unsigned long long)f2bf(v.w) << 48);
    *(unsigned long long*)&dst[off] = p;
}

// ---------- K1: WvSum[j][c] = sum_m Wv[(m*64+j)*C + c]; bvSum[j] ----------
__global__ void k_wvsum(const float* __restrict__ Wv, const float* __restrict__ bv,
                        float* __restrict__ WvSum, float* __restrict__ bvSum) {
    int t = blockIdx.x * 256 + threadIdx.x;   // 131072 = 64*2048
    int j = t >> 11, c = t & 2047;
    float s = 0.f;
    #pragma unroll 8
    for (int m = 0; m < 32; ++m) s += Wv[(m * 64 + j) * CCH + c];
    WvSum[t] = s;
    if (t < 64) {
        float b = 0.f;
        for (int m = 0; m < 32; ++m) b += bv[m * 64 + t];
        bvSum[t] = b;
    }
}

// ---------- K2: Sv[q][j*32+s] = sum_c WvSum[j][c] * x[q][c][s] + bvSum[j] ----------
__global__ void k_sv(const float* __restrict__ x, const float* __restrict__ WvSum,
                     const float* __restrict__ bvSum, float* __restrict__ Sv) {
    int jb = blockIdx.x, q = blockIdx.y;
    int tid = threadIdx.x;
    int s = tid & 31, ty = tid >> 5;
    int j = jb * 8 + ty;
    __shared__ float xs[64][32];
    __shared__ float wsh[8][65];
    float acc = 0.f;
    for (int c0 = 0; c0 < CCH; c0 += 64) {
        for (int idx = tid; idx < 2048; idx += 256)
            xs[idx >> 5][idx & 31] = x[q * 65536 + (c0 + (idx >> 5)) * 32 + (idx & 31)];
        for (int idx = tid; idx < 512; idx += 256)
            wsh[idx >> 6][idx & 63] = WvSum[(jb * 8 + (idx >> 6)) * CCH + c0 + (idx & 63)];
        __syncthreads();
        #pragma unroll
        for (int cc = 0; cc < 64; ++cc)
            acc += wsh[ty][cc] * xs[cc][s];
        __syncthreads();
    }
    Sv[q * CCH + j * 32 + s] = acc + bvSum[j];
}

// ---------- K3: T[q][o] = sum_d Wo[o][d] * Sv[q][d] + bo[o] ----------
__global__ void k_t(const float* __restrict__ Sv, const float* __restrict__ Wo,
                    const float* __restrict__ bo, float* __restrict__ Tm) {
    int ob = blockIdx.x;
    int tid = threadIdx.x;
    int q = tid & 31, ty = tid >> 5;
    int o = ob * 8 + ty;
    __shared__ float svs[32][65];
    __shared__ float wos[8][65];
    float acc = 0.f;
    for (int d0 = 0; d0 < CCH; d0 += 64) {
        for (int idx = tid; idx < 2048; idx += 256)
            svs[idx >> 6][idx & 63] = Sv[(idx >> 6) * CCH + d0 + (idx & 63)];
        for (int idx = tid; idx < 512; idx += 256)
            wos[idx >> 6][idx & 63] = Wo[(ob * 8 + (idx >> 6)) * CCH + d0 + (idx & 63)];
        __syncthreads();
        #pragma unroll
        for (int dd = 0; dd < 64; ++dd)
            acc += wos[ty][dd] * svs[q][dd];
        __syncthreads();
    }
    Tm[q * CCH + o] = acc + bo[o];
}

// ---------- LN1 stats: partial sums of v = 16*T + x ----------
__global__ void k_ln1stat(const float* __restrict__ Tm, const float* __restrict__ x,
                          float* __restrict__ p1, float* __restrict__ p2) {
    int q = blockIdx.x, ch = blockIdx.y;
    int t = threadIdx.x;
    float sum = 0.f, ssq = 0.f;
    for (int j = 0; j < 32; ++j) {
        int i = ch * 8192 + j * 256 + t;
        float v = 16.f * Tm[q * CCH + (i >> 5)] + x[q * 65536 + i];
        sum += v; ssq += v * v;
    }
    #pragma unroll
    for (int off = 32; off > 0; off >>= 1) {
        sum += __shfl_down(sum, off);
        ssq += __shfl_down(ssq, off);
    }
    __shared__ float rs[4], rq[4];
    if ((t & 63) == 0) { rs[t >> 6] = sum; rq[t >> 6] = ssq; }
    __syncthreads();
    if (t == 0) {
        p1[q * 8 + ch] = rs[0] + rs[1] + rs[2] + rs[3];
        p2[q * 8 + ch] = rq[0] + rq[1] + rq[2] + rq[3];
    }
}

__global__ void k_lnfinish(const float* __restrict__ p1, const float* __restrict__ p2,
                           float* __restrict__ stats) {
    int q = blockIdx.x;
    if (threadIdx.x == 0) {
        float S = 0.f, Q = 0.f;
        for (int c = 0; c < 8; ++c) { S += p1[q * 8 + c]; Q += p2[q * 8 + c]; }
        float mu = S * (1.f / 65536.f);
        float var = Q * (1.f / 65536.f) - mu * mu;
        stats[q * 2] = mu;
        stats[q * 2 + 1] = rsqrtf(var + 1e-5f);
    }
}

// ---------- LN1 apply: h1 fp32 [q][c][s] + h1b bf16 transposed [q*32+s][c] ----------
__global__ void k_ln1apply(const float* __restrict__ Tm, const float* __restrict__ x,
                           const float* __restrict__ stats,
                           const float* __restrict__ lnw, const float* __restrict__ lnb,
                           float* __restrict__ h1, u16* __restrict__ h1b) {
    int q = blockIdx.x, cb = blockIdx.y;   // cb: 16 blocks of 128 c
    int t = threadIdx.x;
    float mu = stats[q * 2], rstd = stats[q * 2 + 1];
    __shared__ u16 tile[32 * 132];
    for (int j = 0; j < 16; ++j) {
        int i = cb * 4096 + j * 256 + t;       // c = i>>5, s = i&31
        float v = 16.f * Tm[q * CCH + (i >> 5)] + x[q * 65536 + i];
        float g = (v - mu) * rstd * lnw[i] + lnb[i];
        h1[q * 65536 + i] = g;
        int cl = (j * 256 + t) >> 5;
        tile[(i & 31) * 132 + cl] = f2bf(g);
    }
    __syncthreads();
    for (int j = 0; j < 16; ++j) {
        int idx = j * 256 + t;
        int s = idx >> 7, cl = idx & 127;
        h1b[(size_t)(q * 32 + s) * CCH + cb * 128 + cl] = tile[s * 132 + cl];
    }
}

// ---------- MFMA GEMM (bt): C[m][col] = sum_k A[m][k]*B[col][k] ----------
// EPI 0: relu -> bf16 Out[m][col], ldc=2048   (GEMM1: m=n-token, col=o)
// EPI 1: fp32 out[q*65536 + m*32 + s] = acc + Hres[same], col=(q,s)  (GEMM2)
template<int EPI>
__global__ __launch_bounds__(256) void k_mfma_gemm(
        const u16* __restrict__ A, const u16* __restrict__ B,
        const float* __restrict__ Hres, void* __restrict__ Out) {
    int m0 = blockIdx.x * 128;
    int n0 = blockIdx.y * 64;
    int t = threadIdx.x;
    int lane = t & 63, wid = t >> 6;
    int wm = (wid >> 1) * 64, wn = (wid & 1) * 32;
    int l15 = lane & 15, lk = (lane >> 4) * 8;

    __shared__ u16 Atile[128 * 64];
    __shared__ u16 Btile[64 * 64];

    f32x4 acc[4][2];
    f32x4 z = {0.f, 0.f, 0.f, 0.f};
    #pragma unroll
    for (int a = 0; a < 4; ++a)
        #pragma unroll
        for (int b = 0; b < 2; ++b) acc[a][b] = z;

    int srow = t >> 3;          // 0..31
    int scol = (t & 7) * 8;     // element offset of 16B chunk

    for (int k0 = 0; k0 < CCH; k0 += 64) {
        #pragma unroll
        for (int i = 0; i < 4; ++i)
            gload_lds16(A + (size_t)(m0 + i * 32 + srow) * CCH + k0 + scol,
                        &Atile[i * 2048 + t * 8]);
        #pragma unroll
        for (int i = 0; i < 2; ++i)
            gload_lds16(B + (size_t)(n0 + i * 32 + srow) * CCH + k0 + scol,
                        &Btile[i * 2048 + t * 8]);
        __syncthreads();
        #pragma unroll
        for (int ks = 0; ks < 2; ++ks) {
            bf16x8 af[4], bf[2];
            #pragma unroll
            for (int fm = 0; fm < 4; ++fm)
                af[fm] = *(const bf16x8*)&Atile[(wm + fm * 16 + l15) * 64 + ks * 32 + lk];
            #pragma unroll
            for (int fn = 0; fn < 2; ++fn)
                bf[fn] = *(const bf16x8*)&Btile[(wn + fn * 16 + l15) * 64 + ks * 32 + lk];
            #pragma unroll
            for (int fm = 0; fm < 4; ++fm)
                #pragma unroll
                for (int fn = 0; fn < 2; ++fn)
                    acc[fm][fn] = __builtin_amdgcn_mfma_f32_16x16x32_bf16(
                        af[fm], bf[fn], acc[fm][fn], 0, 0, 0);
        }
        __syncthreads();
    }

    #pragma unroll
    for (int fm = 0; fm < 4; ++fm) {
        #pragma unroll
        for (int fn = 0; fn < 2; ++fn) {
            #pragma unroll
            for (int r = 0; r < 4; ++r) {
                int mg = m0 + wm + fm * 16 + (lane >> 4) * 4 + r;
                int cg = n0 + wn + fn * 16 + l15;
                float v = acc[fm][fn][r];
                if (EPI == 0) {
                    ((u16*)Out)[(size_t)mg * 2048 + cg] = f2bf(fmaxf(v, 0.f));
                } else {
                    int q = cg >> 5, s = cg & 31;
                    size_t addr = (size_t)q * 65536 + (size_t)mg * 32 + s;
                    ((float*)Out)[addr] = v + Hres[addr];
                }
            }
        }
    }
}

// ---------- LN2 stats on out ----------
__global__ void k_ln2stat(const float* __restrict__ io,
                          float* __restrict__ p1, float* __restrict__ p2) {
    int q = blockIdx.x, ch = blockIdx.y;
    int t = threadIdx.x;
    float sum = 0.f, ssq = 0.f;
    for (int j = 0; j < 32; ++j) {
        float v = io[q * 65536 + ch * 8192 + j * 256 + t];
        sum += v; ssq += v * v;
    }
    #pragma unroll
    for (int off = 32; off > 0; off >>= 1) {
        sum += __shfl_down(sum, off);
        ssq += __shfl_down(ssq, off);
    }
    __shared__ float rs[4], rq[4];
    if ((t & 63) == 0) { rs[t >> 6] = sum; rq[t >> 6] = ssq; }
    __syncthreads();
    if (t == 0) {
        p1[q * 8 + ch] = rs[0] + rs[1] + rs[2] + rs[3];
        p2[q * 8 + ch] = rq[0] + rq[1] + rq[2] + rq[3];
    }
}

__global__ void k_ln2apply(float* __restrict__ io, const float* __restrict__ stats,
                           const float* __restrict__ lnw, const float* __restrict__ lnb) {
    int q = blockIdx.x, cb = blockIdx.y;
    int t = threadIdx.x;
    float mu = stats[q * 2], rstd = stats[q * 2 + 1];
    for (int j = 0; j < 16; ++j) {
        int i = cb * 4096 + j * 256 + t;
        float v = io[q * 65536 + i];
        io[q * 65536 + i] = (v - mu) * rstd * lnw[i] + lnb[i];
    }
}

extern "C" void kernel_launch(void* const* d_in, const int* in_sizes, int n_in,
                              void* d_out, int out_size, void* d_ws, size_t ws_size,
                              hipStream_t stream) {
    const float* x    = (const float*)d_in[0];
    const float* Wv   = (const float*)d_in[6];
    const float* bv   = (const float*)d_in[7];
    const float* Wo   = (const float*)d_in[8];
    const float* bo   = (const float*)d_in[9];
    const float* W1   = (const float*)d_in[10];
    const float* W2   = (const float*)d_in[11];
    const float* ln1w = (const float*)d_in[12];
    const float* ln1b = (const float*)d_in[13];
    const float* ln2w = (const float*)d_in[14];
    const float* ln2b = (const float*)d_in[15];
    float* out = (float*)d_out;

    float* ws    = (float*)d_ws;
    float* WvSum = ws;                   // 131072
    float* bvSum = ws + 131072;          // 64 -> pad 131136
    float* Sv    = ws + 131136;          // 65536 -> 196672
    float* Tm    = ws + 196672;          // 65536 -> 262208
    float* h1    = ws + 262208;          // 2097152 -> 2359360
    float* stats = ws + 2359360;         // 64 -> 2359424
    float* p1    = ws + 2359424;         // 256 -> 2359680
    float* p2    = ws + 2359680;         // 256 -> 2359936
    u16* ub      = (u16*)(ws + 2359936);
    u16* h1b     = ub;                   // 2097152
    u16* Y1b     = ub + 2097152;         // 2097152
    u16* W1b     = ub + 4194304;         // 4194304
    u16* W2b     = ub + 8388608;         // 4194304  (total ~34 MB)

    k_convert<<<8192, 256, 0, stream>>>(W1, W2, W1b, W2b);
    k_wvsum<<<512, 256, 0, stream>>>(Wv, bv, WvSum, bvSum);
    k_sv<<<dim3(8, 32), 256, 0, stream>>>(x, WvSum, bvSum, Sv);
    k_t<<<256, 256, 0, stream>>>(Sv, Wo, bo, Tm);
    k_ln1stat<<<dim3(32, 8), 256, 0, stream>>>(Tm, x, p1, p2);
    k_lnfinish<<<32, 64, 0, stream>>>(p1, p2, stats);
    k_ln1apply<<<dim3(32, 16), 256, 0, stream>>>(Tm, x, stats, ln1w, ln1b, h1, h1b);
    // GEMM1: M=1024 (tokens), N=2048 (o): grid (8, 32)
    k_mfma_gemm<0><<<dim3(8, 32), 256, 0, stream>>>(h1b, W1b, nullptr, Y1b);
    // GEMM2: M=2048 (o), N=1024 (tokens): grid (16, 16)
    k_mfma_gemm<1><<<dim3(16, 16), 256, 0, stream>>>(W2b, Y1b, h1, out);
    k_ln2stat<<<dim3(32, 8), 256, 0, stream>>>(out, p1, p2);
    k_lnfinish<<<32, 64, 0, stream>>>(p1, p2, stats);
    k_ln2apply<<<dim3(32, 16), 256, 0, stream>>>(out, stats, ln2w, ln2b);
}

// Round 3
// 146.795 us; speedup vs baseline: 3.7646x; 1.7081x over previous
//
#include <hip/hip_runtime.h>

typedef unsigned short u16;
typedef unsigned int u32;
typedef __attribute__((ext_vector_type(8))) short bf16x8;
typedef __attribute__((ext_vector_type(4))) float f32x4;

#define CCH 2048

__device__ __forceinline__ u16 f2bf(float f) {
    unsigned int x = __float_as_uint(f);
    unsigned int r = (x + 0x7fffu + ((x >> 16) & 1u)) >> 16;
    return (u16)r;
}

__device__ __forceinline__ void gload_lds16(const u16* g, u16* l) {
    __builtin_amdgcn_global_load_lds((const __attribute__((address_space(1))) void*)g,
                                     (__attribute__((address_space(3))) void*)l, 16, 0, 0);
}

// ---------- convert W1, W2, Wo fp32 -> bf16 ----------
__global__ void k_convert3(const float* __restrict__ W1, const float* __restrict__ W2,
                           const float* __restrict__ Wo,
                           u16* __restrict__ W1b, u16* __restrict__ W2b, u16* __restrict__ Wob) {
    long tg = (long)blockIdx.x * 256 + threadIdx.x;   // 3145728 threads, 4 elems each
    long base = tg * 4;
    const float* src; u16* dst; long off;
    if (base < 4194304)      { src = W1; dst = W1b; off = base; }
    else if (base < 8388608) { src = W2; dst = W2b; off = base - 4194304; }
    else                     { src = Wo; dst = Wob; off = base - 8388608; }
    float4 v = *(const float4*)&src[off];
    unsigned long long p = (unsigned long long)f2bf(v.x)
                         | ((unsigned long long)f2bf(v.y) << 16)
                         | ((unsigned long long)f2bf(v.z) << 32)
                         | ((unsigned long long)f2bf(v.w) << 48);
    *(unsigned long long*)&dst[off] = p;
}

// ---------- WvSumb[j][c] = bf16( sum_{m<32} Wv[(m*64+j)*C + c] ); bvSum fp32 ----------
__global__ void k_wvsum(const float* __restrict__ Wv, const float* __restrict__ bv,
                        u16* __restrict__ WvSumb, float* __restrict__ bvSum) {
    int t = blockIdx.x * 256 + threadIdx.x;   // 131072 = 64*2048
    int j = t >> 11;
    float s = 0.f;
    #pragma unroll 8
    for (int m = 0; m < 32; ++m) s += Wv[(m * 64 + j) * CCH + (t & 2047)];
    WvSumb[t] = f2bf(s);
    if (t < 64) {
        float b = 0.f;
        for (int m = 0; m < 32; ++m) b += bv[m * 64 + t];
        bvSum[t] = b;
    }
}

// ---------- x [q][c][s] fp32 -> xTb [(q*32+s)][c] bf16 ----------
__global__ void k_xpose(const float* __restrict__ x, u16* __restrict__ xTb) {
    int cb = blockIdx.x, q = blockIdx.y;   // 32 c-blocks of 64, 32 q
    int t = threadIdx.x;
    int c0 = cb * 64;
    __shared__ float ftile[32][33];  // wait: need [s up to 32][c up to 64] -> use [64][33]? see below
    // We process two half-tiles of 32 c each to keep LDS small and patterns simple.
    u32* xT32 = (u32*)xTb;
    #pragma unroll
    for (int half = 0; half < 2; ++half) {
        int ch = c0 + half * 32;
        // load 32c x 32s floats, transposed into ftile[s][c]
        {
            int idx = t;                       // 256 threads
            #pragma unroll
            for (int k = 0; k < 4; ++k) {
                int i = idx + k * 256;         // i < 1024: c = i>>5, s = i&31
                ftile[i & 31][i >> 5] = x[q * 65536 + (ch + (i >> 5)) * 32 + (i & 31)];
            }
        }
        __syncthreads();
        // write: rows s, 32 c as 16 u32 per row
        {
            #pragma unroll
            for (int k = 0; k < 2; ++k) {
                int i = t + k * 256;           // i < 512: s = i>>4, cp = i&15
                int s = i >> 4, cp = i & 15;
                u32 val = (u32)f2bf(ftile[s][cp * 2]) | ((u32)f2bf(ftile[s][cp * 2 + 1]) << 16);
                xT32[(size_t)(q * 32 + s) * 1024 + (ch >> 1) + cp] = val;
            }
        }
        __syncthreads();
    }
}

// ---------- Sv GEMM: P[kc][j][col] = sum_{k in chunk} WvSumb[j][k] * xTb[col][k] ----------
__global__ __launch_bounds__(256) void k_sv_gemm(const u16* __restrict__ A, const u16* __restrict__ B,
                                                 float* __restrict__ P) {
    int n0 = blockIdx.x * 64;     // 16 col tiles
    int kc = blockIdx.y;          // 4 k-chunks of 512
    int t = threadIdx.x;
    int lane = t & 63, wid = t >> 6;
    int wm = wid * 16;
    int l15 = lane & 15, lk = (lane >> 4) * 8;
    __shared__ u16 At[2][64 * 64];
    __shared__ u16 Bt[2][64 * 64];
    f32x4 z = {0.f, 0.f, 0.f, 0.f};
    f32x4 acc[4] = {z, z, z, z};
    int srow = t >> 3, scol = (t & 7) * 8;
    int kbase = kc * 512;

    auto STAGE = [&](int p, int k0) {
        #pragma unroll
        for (int i = 0; i < 2; ++i) {
            gload_lds16(A + (size_t)(i * 32 + srow) * CCH + k0 + scol, &At[p][i * 2048 + t * 8]);
            gload_lds16(B + (size_t)(n0 + i * 32 + srow) * CCH + k0 + scol, &Bt[p][i * 2048 + t * 8]);
        }
    };
    STAGE(0, kbase);
    __syncthreads();
    int cur = 0;
    for (int kt = 0; kt < 8; ++kt) {
        if (kt < 7) STAGE(cur ^ 1, kbase + (kt + 1) * 64);
        #pragma unroll
        for (int ks = 0; ks < 2; ++ks) {
            bf16x8 af = *(const bf16x8*)&At[cur][(wm + l15) * 64 + ks * 32 + lk];
            #pragma unroll
            for (int fn = 0; fn < 4; ++fn) {
                bf16x8 bf = *(const bf16x8*)&Bt[cur][(fn * 16 + l15) * 64 + ks * 32 + lk];
                acc[fn] = __builtin_amdgcn_mfma_f32_16x16x32_bf16(af, bf, acc[fn], 0, 0, 0);
            }
        }
        __syncthreads();
        cur ^= 1;
    }
    #pragma unroll
    for (int fn = 0; fn < 4; ++fn)
        #pragma unroll
        for (int r = 0; r < 4; ++r) {
            int j = wm + (lane >> 4) * 4 + r;
            int col = n0 + fn * 16 + l15;
            P[kc * 65536 + j * 1024 + col] = acc[fn][r];
        }
}

// ---------- Sv reduce: Svb[q][j*32+s] = bf16( sum_kc P + bvSum[j] ) ----------
__global__ void k_sv_reduce(const float* __restrict__ P, const float* __restrict__ bvSum,
                            u16* __restrict__ Svb) {
    int idx0 = blockIdx.x * 1024 + threadIdx.x;
    #pragma unroll
    for (int k = 0; k < 4; ++k) {
        int idx = idx0 + k * 256;            // [0, 65536)
        int j = idx >> 10, col = idx & 1023;
        float v = bvSum[j];
        #pragma unroll
        for (int kc = 0; kc < 4; ++kc) v += P[kc * 65536 + idx];
        Svb[(size_t)(col >> 5) * CCH + j * 32 + (col & 31)] = f2bf(v);
    }
}

// ---------- T GEMM: P[kc][o][q] = sum_{k in chunk} Wob[o][k] * Svb[q][k] ----------
__global__ __launch_bounds__(256) void k_t_gemm(const u16* __restrict__ A, const u16* __restrict__ B,
                                                float* __restrict__ P) {
    int m0 = blockIdx.x * 128;   // 16 o tiles
    int kc = blockIdx.y;         // 4 chunks of 512
    int t = threadIdx.x;
    int lane = t & 63, wid = t >> 6;
    int wm = wid * 32;
    int l15 = lane & 15, lk = (lane >> 4) * 8;
    __shared__ u16 At[2][128 * 64];
    __shared__ u16 Bt[2][32 * 64];
    f32x4 z = {0.f, 0.f, 0.f, 0.f};
    f32x4 acc[2][2] = {{z, z}, {z, z}};
    int srow = t >> 3, scol = (t & 7) * 8;
    int kbase = kc * 512;

    auto STAGE = [&](int p, int k0) {
        #pragma unroll
        for (int i = 0; i < 4; ++i)
            gload_lds16(A + (size_t)(m0 + i * 32 + srow) * CCH + k0 + scol, &At[p][i * 2048 + t * 8]);
        gload_lds16(B + (size_t)srow * CCH + k0 + scol, &Bt[p][t * 8]);
    };
    STAGE(0, kbase);
    __syncthreads();
    int cur = 0;
    for (int kt = 0; kt < 8; ++kt) {
        if (kt < 7) STAGE(cur ^ 1, kbase + (kt + 1) * 64);
        #pragma unroll
        for (int ks = 0; ks < 2; ++ks) {
            bf16x8 af[2], bf[2];
            #pragma unroll
            for (int fm = 0; fm < 2; ++fm)
                af[fm] = *(const bf16x8*)&At[cur][(wm + fm * 16 + l15) * 64 + ks * 32 + lk];
            #pragma unroll
            for (int fn = 0; fn < 2; ++fn)
                bf[fn] = *(const bf16x8*)&Bt[cur][(fn * 16 + l15) * 64 + ks * 32 + lk];
            #pragma unroll
            for (int fm = 0; fm < 2; ++fm)
                #pragma unroll
                for (int fn = 0; fn < 2; ++fn)
                    acc[fm][fn] = __builtin_amdgcn_mfma_f32_16x16x32_bf16(af[fm], bf[fn], acc[fm][fn], 0, 0, 0);
        }
        __syncthreads();
        cur ^= 1;
    }
    #pragma unroll
    for (int fm = 0; fm < 2; ++fm)
        #pragma unroll
        for (int fn = 0; fn < 2; ++fn)
            #pragma unroll
            for (int r = 0; r < 4; ++r) {
                int mg = m0 + wm + fm * 16 + (lane >> 4) * 4 + r;
                int cg = fn * 16 + l15;
                P[kc * 65536 + mg * 32 + cg] = acc[fm][fn][r];
            }
}

// ---------- T reduce (+transpose): Tm[q][o] = sum_kc P[kc][o][q] + bo[o] ----------
__global__ void k_t_reduce(const float* __restrict__ P, const float* __restrict__ bo,
                           float* __restrict__ Tm) {
    int idx0 = blockIdx.x * 1024 + threadIdx.x;
    #pragma unroll
    for (int k = 0; k < 4; ++k) {
        int idx = idx0 + k * 256;           // q = idx>>11, o = idx&2047
        int q = idx >> 11, o = idx & 2047;
        float v = bo[o];
        #pragma unroll
        for (int kc = 0; kc < 4; ++kc) v += P[kc * 65536 + o * 32 + q];
        Tm[q * CCH + o] = v;
    }
}

// ---------- LN1 stats: partial sums of v = 16*T + x ----------
__global__ void k_ln1stat(const float* __restrict__ Tm, const float* __restrict__ x,
                          float* __restrict__ p1, float* __restrict__ p2) {
    int q = blockIdx.x, ch = blockIdx.y;
    int t = threadIdx.x;
    float sum = 0.f, ssq = 0.f;
    for (int j = 0; j < 32; ++j) {
        int i = ch * 8192 + j * 256 + t;
        float v = 16.f * Tm[q * CCH + (i >> 5)] + x[q * 65536 + i];
        sum += v; ssq += v * v;
    }
    #pragma unroll
    for (int off = 32; off > 0; off >>= 1) {
        sum += __shfl_down(sum, off);
        ssq += __shfl_down(ssq, off);
    }
    __shared__ float rs[4], rq[4];
    if ((t & 63) == 0) { rs[t >> 6] = sum; rq[t >> 6] = ssq; }
    __syncthreads();
    if (t == 0) {
        p1[q * 8 + ch] = rs[0] + rs[1] + rs[2] + rs[3];
        p2[q * 8 + ch] = rq[0] + rq[1] + rq[2] + rq[3];
    }
}

__global__ void k_lnfinish(const float* __restrict__ p1, const float* __restrict__ p2,
                           float* __restrict__ stats) {
    int q = blockIdx.x;
    if (threadIdx.x == 0) {
        float S = 0.f, Q = 0.f;
        for (int c = 0; c < 8; ++c) { S += p1[q * 8 + c]; Q += p2[q * 8 + c]; }
        float mu = S * (1.f / 65536.f);
        float var = Q * (1.f / 65536.f) - mu * mu;
        stats[q * 2] = mu;
        stats[q * 2 + 1] = rsqrtf(var + 1e-5f);
    }
}

// ---------- LN1 apply: h1 fp32 [q][c][s] + h1b bf16 transposed [q*32+s][c] ----------
__global__ void k_ln1apply(const float* __restrict__ Tm, const float* __restrict__ x,
                           const float* __restrict__ stats,
                           const float* __restrict__ lnw, const float* __restrict__ lnb,
                           float* __restrict__ h1, u16* __restrict__ h1b) {
    int q = blockIdx.x, cb = blockIdx.y;   // cb: 16 blocks of 128 c
    int t = threadIdx.x;
    float mu = stats[q * 2], rstd = stats[q * 2 + 1];
    __shared__ u16 tile[32 * 132];
    for (int j = 0; j < 16; ++j) {
        int i = cb * 4096 + j * 256 + t;       // c = i>>5, s = i&31
        float v = 16.f * Tm[q * CCH + (i >> 5)] + x[q * 65536 + i];
        float g = (v - mu) * rstd * lnw[i] + lnb[i];
        h1[q * 65536 + i] = g;
        int cl = (j * 256 + t) >> 5;
        tile[(i & 31) * 132 + cl] = f2bf(g);
    }
    __syncthreads();
    for (int j = 0; j < 16; ++j) {
        int idx = j * 256 + t;
        int s = idx >> 7, cl = idx & 127;
        h1b[(size_t)(q * 32 + s) * CCH + cb * 128 + cl] = tile[s * 132 + cl];
    }
}

// ---------- MFMA GEMM (bt, 2-phase dbuf): C[m][col] = sum_k A[m][k]*B[col][k] ----------
// EPI 0: relu -> bf16 Out[m][col], ldc=2048   (GEMM1)
// EPI 1: fp32 out[q*65536 + m*32 + s] = acc + Hres, col=(q,s)  (GEMM2)
template<int EPI>
__global__ __launch_bounds__(256) void k_mfma_gemm(
        const u16* __restrict__ A, const u16* __restrict__ B,
        const float* __restrict__ Hres, void* __restrict__ Out) {
    int m0 = blockIdx.x * 128;
    int n0 = blockIdx.y * 64;
    int t = threadIdx.x;
    int lane = t & 63, wid = t >> 6;
    int wm = (wid >> 1) * 64, wn = (wid & 1) * 32;
    int l15 = lane & 15, lk = (lane >> 4) * 8;

    __shared__ u16 Atile[2][128 * 64];
    __shared__ u16 Btile[2][64 * 64];

    f32x4 z = {0.f, 0.f, 0.f, 0.f};
    f32x4 acc[4][2] = {{z, z}, {z, z}, {z, z}, {z, z}};

    int srow = t >> 3;
    int scol = (t & 7) * 8;

    auto STAGE = [&](int p, int k0) {
        #pragma unroll
        for (int i = 0; i < 4; ++i)
            gload_lds16(A + (size_t)(m0 + i * 32 + srow) * CCH + k0 + scol,
                        &Atile[p][i * 2048 + t * 8]);
        #pragma unroll
        for (int i = 0; i < 2; ++i)
            gload_lds16(B + (size_t)(n0 + i * 32 + srow) * CCH + k0 + scol,
                        &Btile[p][i * 2048 + t * 8]);
    };

    STAGE(0, 0);
    __syncthreads();
    int cur = 0;
    for (int kt = 0; kt < 32; ++kt) {
        if (kt < 31) STAGE(cur ^ 1, (kt + 1) * 64);
        #pragma unroll
        for (int ks = 0; ks < 2; ++ks) {
            bf16x8 af[4], bf[2];
            #pragma unroll
            for (int fm = 0; fm < 4; ++fm)
                af[fm] = *(const bf16x8*)&Atile[cur][(wm + fm * 16 + l15) * 64 + ks * 32 + lk];
            #pragma unroll
            for (int fn = 0; fn < 2; ++fn)
                bf[fn] = *(const bf16x8*)&Btile[cur][(wn + fn * 16 + l15) * 64 + ks * 32 + lk];
            #pragma unroll
            for (int fm = 0; fm < 4; ++fm)
                #pragma unroll
                for (int fn = 0; fn < 2; ++fn)
                    acc[fm][fn] = __builtin_amdgcn_mfma_f32_16x16x32_bf16(
                        af[fm], bf[fn], acc[fm][fn], 0, 0, 0);
        }
        __syncthreads();
        cur ^= 1;
    }

    #pragma unroll
    for (int fm = 0; fm < 4; ++fm) {
        #pragma unroll
        for (int fn = 0; fn < 2; ++fn) {
            #pragma unroll
            for (int r = 0; r < 4; ++r) {
                int mg = m0 + wm + fm * 16 + (lane >> 4) * 4 + r;
                int cg = n0 + wn + fn * 16 + l15;
                float v = acc[fm][fn][r];
                if (EPI == 0) {
                    ((u16*)Out)[(size_t)mg * 2048 + cg] = f2bf(fmaxf(v, 0.f));
                } else {
                    int q = cg >> 5, s = cg & 31;
                    size_t addr = (size_t)q * 65536 + (size_t)mg * 32 + s;
                    ((float*)Out)[addr] = v + Hres[addr];
                }
            }
        }
    }
}

// ---------- LN2 stats on out ----------
__global__ void k_ln2stat(const float* __restrict__ io,
                          float* __restrict__ p1, float* __restrict__ p2) {
    int q = blockIdx.x, ch = blockIdx.y;
    int t = threadIdx.x;
    float sum = 0.f, ssq = 0.f;
    for (int j = 0; j < 32; ++j) {
        float v = io[q * 65536 + ch * 8192 + j * 256 + t];
        sum += v; ssq += v * v;
    }
    #pragma unroll
    for (int off = 32; off > 0; off >>= 1) {
        sum += __shfl_down(sum, off);
        ssq += __shfl_down(ssq, off);
    }
    __shared__ float rs[4], rq[4];
    if ((t & 63) == 0) { rs[t >> 6] = sum; rq[t >> 6] = ssq; }
    __syncthreads();
    if (t == 0) {
        p1[q * 8 + ch] = rs[0] + rs[1] + rs[2] + rs[3];
        p2[q * 8 + ch] = rq[0] + rq[1] + rq[2] + rq[3];
    }
}

__global__ void k_ln2apply(float* __restrict__ io, const float* __restrict__ stats,
                           const float* __restrict__ lnw, const float* __restrict__ lnb) {
    int q = blockIdx.x, cb = blockIdx.y;
    int t = threadIdx.x;
    float mu = stats[q * 2], rstd = stats[q * 2 + 1];
    for (int j = 0; j < 16; ++j) {
        int i = cb * 4096 + j * 256 + t;
        float v = io[q * 65536 + i];
        io[q * 65536 + i] = (v - mu) * rstd * lnw[i] + lnb[i];
    }
}

extern "C" void kernel_launch(void* const* d_in, const int* in_sizes, int n_in,
                              void* d_out, int out_size, void* d_ws, size_t ws_size,
                              hipStream_t stream) {
    const float* x    = (const float*)d_in[0];
    const float* Wv   = (const float*)d_in[6];
    const float* bv   = (const float*)d_in[7];
    const float* Wo   = (const float*)d_in[8];
    const float* bo   = (const float*)d_in[9];
    const float* W1   = (const float*)d_in[10];
    const float* W2   = (const float*)d_in[11];
    const float* ln1w = (const float*)d_in[12];
    const float* ln1b = (const float*)d_in[13];
    const float* ln2w = (const float*)d_in[14];
    const float* ln2b = (const float*)d_in[15];
    float* out = (float*)d_out;

    float* ws    = (float*)d_ws;
    float* bvSum = ws;                    // 64
    float* stats = ws + 64;               // 64
    float* p1    = ws + 128;              // 256
    float* p2    = ws + 384;              // 256
    float* Psv   = ws + 640;              // 262144
    float* Pt    = ws + 262784;           // 262144
    float* Tm    = ws + 524928;           // 65536
    float* h1    = ws + 590464;           // 2097152 -> 2687616 floats
    u16* ub      = (u16*)(ws + 2687616);
    u16* WvSumb  = ub;                    // 131072
    u16* xTb     = ub + 131072;           // 2097152
    u16* Svb     = ub + 2228224;          // 65536
    u16* h1b     = ub + 2293760;          // 2097152
    u16* Y1b     = ub + 4390912;          // 2097152
    u16* W1b     = ub + 6488064;          // 4194304
    u16* W2b     = ub + 10682368;         // 4194304
    u16* Wob     = ub + 14876672;         // 4194304 -> total ~48.9 MB

    k_convert3<<<12288, 256, 0, stream>>>(W1, W2, Wo, W1b, W2b, Wob);
    k_wvsum<<<512, 256, 0, stream>>>(Wv, bv, WvSumb, bvSum);
    k_xpose<<<dim3(32, 32), 256, 0, stream>>>(x, xTb);
    k_sv_gemm<<<dim3(16, 4), 256, 0, stream>>>(WvSumb, xTb, Psv);
    k_sv_reduce<<<64, 256, 0, stream>>>(Psv, bvSum, Svb);
    k_t_gemm<<<dim3(16, 4), 256, 0, stream>>>(Wob, Svb, Pt);
    k_t_reduce<<<64, 256, 0, stream>>>(Pt, bo, Tm);
    k_ln1stat<<<dim3(32, 8), 256, 0, stream>>>(Tm, x, p1, p2);
    k_lnfinish<<<32, 64, 0, stream>>>(p1, p2, stats);
    k_ln1apply<<<dim3(32, 16), 256, 0, stream>>>(Tm, x, stats, ln1w, ln1b, h1, h1b);
    // GEMM1: M=1024 (tokens), N=2048 (o)
    k_mfma_gemm<0><<<dim3(8, 32), 256, 0, stream>>>(h1b, W1b, nullptr, Y1b);
    // GEMM2: M=2048 (o), N=1024 (tokens)
    k_mfma_gemm<1><<<dim3(16, 16), 256, 0, stream>>>(W2b, Y1b, h1, out);
    k_ln2stat<<<dim3(32, 8), 256, 0, stream>>>(out, p1, p2);
    k_lnfinish<<<32, 64, 0, stream>>>(p1, p2, stats);
    k_ln2apply<<<dim3(32, 16), 256, 0, stream>>>(out, stats, ln2w, ln2b);
}

// Round 4
// 114.190 us; speedup vs baseline: 4.8395x; 1.2855x over previous
//
#include <hip/hip_runtime.h>

typedef unsigned short u16;
typedef unsigned int u32;
typedef unsigned long long u64;
typedef __attribute__((ext_vector_type(8))) short bf16x8;
typedef __attribute__((ext_vector_type(4))) float f32x4;

#define CCH 2048

__device__ __forceinline__ u16 f2bf(float f) {
    unsigned int x = __float_as_uint(f);
    unsigned int r = (x + 0x7fffu + ((x >> 16) & 1u)) >> 16;
    return (u16)r;
}

__device__ __forceinline__ void gload_lds16(const u16* g, u16* l) {
    __builtin_amdgcn_global_load_lds((const __attribute__((address_space(1))) void*)g,
                                     (__attribute__((address_space(3))) void*)l, 16, 0, 0);
}

// ---------- convert W1, W2, Wo fp32 -> bf16 ----------
__global__ void k_convert3(const float* __restrict__ W1, const float* __restrict__ W2,
                           const float* __restrict__ Wo,
                           u16* __restrict__ W1b, u16* __restrict__ W2b, u16* __restrict__ Wob) {
    long tg = (long)blockIdx.x * 256 + threadIdx.x;
    long base = tg * 4;
    const float* src; u16* dst; long off;
    if (base < 4194304)      { src = W1; dst = W1b; off = base; }
    else if (base < 8388608) { src = W2; dst = W2b; off = base - 4194304; }
    else                     { src = Wo; dst = Wob; off = base - 8388608; }
    float4 v = *(const float4*)&src[off];
    u64 p = (u64)f2bf(v.x) | ((u64)f2bf(v.y) << 16) | ((u64)f2bf(v.z) << 32) | ((u64)f2bf(v.w) << 48);
    *(u64*)&dst[off] = p;
}

// ---------- WvSumb[j][c] = bf16( sum_m Wv[(m*64+j)*C + c] ); bvSum fp32 ----------
__global__ void k_wvsum(const float* __restrict__ Wv, const float* __restrict__ bv,
                        u16* __restrict__ WvSumb, float* __restrict__ bvSum) {
    int t = blockIdx.x * 256 + threadIdx.x;
    int j = t >> 11;
    float s = 0.f;
    #pragma unroll 8
    for (int m = 0; m < 32; ++m) s += Wv[(m * 64 + j) * CCH + (t & 2047)];
    WvSumb[t] = f2bf(s);
    if (t < 64) {
        float b = 0.f;
        for (int m = 0; m < 32; ++m) b += bv[m * 64 + t];
        bvSum[t] = b;
    }
}

// ---------- x [q][c][s] fp32 -> xTb [(q*32+s)][c] bf16 ----------
__global__ void k_xpose(const float* __restrict__ x, u16* __restrict__ xTb) {
    int cb = blockIdx.x, q = blockIdx.y;
    int t = threadIdx.x;
    int c0 = cb * 64;
    __shared__ float ftile[32][33];
    u32* xT32 = (u32*)xTb;
    #pragma unroll
    for (int half = 0; half < 2; ++half) {
        int ch = c0 + half * 32;
        #pragma unroll
        for (int k = 0; k < 4; ++k) {
            int i = t + k * 256;
            ftile[i & 31][i >> 5] = x[q * 65536 + (ch + (i >> 5)) * 32 + (i & 31)];
        }
        __syncthreads();
        #pragma unroll
        for (int k = 0; k < 2; ++k) {
            int i = t + k * 256;
            int s = i >> 4, cp = i & 15;
            u32 val = (u32)f2bf(ftile[s][cp * 2]) | ((u32)f2bf(ftile[s][cp * 2 + 1]) << 16);
            xT32[(size_t)(q * 32 + s) * 1024 + (ch >> 1) + cp] = val;
        }
        __syncthreads();
    }
}

// ---------- Sv GEMM: P[kc][j][col] = sum_k WvSumb[j][k] * xTb[col][k] ----------
__global__ __launch_bounds__(256) void k_sv_gemm(const u16* __restrict__ A, const u16* __restrict__ B,
                                                 float* __restrict__ P) {
    int n0 = blockIdx.x * 64;
    int kc = blockIdx.y;
    int t = threadIdx.x;
    int lane = t & 63, wid = t >> 6;
    int wm = wid * 16;
    int l15 = lane & 15, lhi = lane >> 4, sw = l15 & 7;
    int offk[2] = { ((lhi) ^ sw) * 8, ((4 + lhi) ^ sw) * 8 };
    __shared__ u16 At[2][64 * 64];
    __shared__ u16 Bt[2][64 * 64];
    f32x4 z = {0.f, 0.f, 0.f, 0.f};
    f32x4 acc[4] = {z, z, z, z};
    int srow = t >> 3, scol = ((t & 7) ^ (srow & 7)) * 8;
    int kbase = kc * 512;

    auto STAGE = [&](int p, int k0) {
        #pragma unroll
        for (int i = 0; i < 2; ++i) {
            gload_lds16(A + (size_t)(i * 32 + srow) * CCH + k0 + scol, &At[p][i * 2048 + t * 8]);
            gload_lds16(B + (size_t)(n0 + i * 32 + srow) * CCH + k0 + scol, &Bt[p][i * 2048 + t * 8]);
        }
    };
    STAGE(0, kbase);
    __syncthreads();
    int cur = 0;
    for (int kt = 0; kt < 8; ++kt) {
        if (kt < 7) STAGE(cur ^ 1, kbase + (kt + 1) * 64);
        #pragma unroll
        for (int ks = 0; ks < 2; ++ks) {
            bf16x8 af = *(const bf16x8*)&At[cur][(wm + l15) * 64 + offk[ks]];
            #pragma unroll
            for (int fn = 0; fn < 4; ++fn) {
                bf16x8 bf = *(const bf16x8*)&Bt[cur][(fn * 16 + l15) * 64 + offk[ks]];
                acc[fn] = __builtin_amdgcn_mfma_f32_16x16x32_bf16(af, bf, acc[fn], 0, 0, 0);
            }
        }
        __syncthreads();
        cur ^= 1;
    }
    #pragma unroll
    for (int fn = 0; fn < 4; ++fn)
        #pragma unroll
        for (int r = 0; r < 4; ++r) {
            int j = wm + lhi * 4 + r;
            int col = n0 + fn * 16 + l15;
            P[kc * 65536 + j * 1024 + col] = acc[fn][r];
        }
}

// ---------- Sv reduce ----------
__global__ void k_sv_reduce(const float* __restrict__ P, const float* __restrict__ bvSum,
                            u16* __restrict__ Svb) {
    int idx0 = blockIdx.x * 1024 + threadIdx.x;
    #pragma unroll
    for (int k = 0; k < 4; ++k) {
        int idx = idx0 + k * 256;
        int j = idx >> 10, col = idx & 1023;
        float v = bvSum[j];
        #pragma unroll
        for (int kc = 0; kc < 4; ++kc) v += P[kc * 65536 + idx];
        Svb[(size_t)(col >> 5) * CCH + j * 32 + (col & 31)] = f2bf(v);
    }
}

// ---------- T GEMM: P[kc][o][q] = sum_k Wob[o][k] * Svb[q][k] ----------
__global__ __launch_bounds__(256) void k_t_gemm(const u16* __restrict__ A, const u16* __restrict__ B,
                                                float* __restrict__ P) {
    int m0 = blockIdx.x * 128;
    int kc = blockIdx.y;
    int t = threadIdx.x;
    int lane = t & 63, wid = t >> 6;
    int wm = wid * 32;
    int l15 = lane & 15, lhi = lane >> 4, sw = l15 & 7;
    int offk[2] = { ((lhi) ^ sw) * 8, ((4 + lhi) ^ sw) * 8 };
    __shared__ u16 At[2][128 * 64];
    __shared__ u16 Bt[2][32 * 64];
    f32x4 z = {0.f, 0.f, 0.f, 0.f};
    f32x4 acc[2][2] = {{z, z}, {z, z}};
    int srow = t >> 3, scol = ((t & 7) ^ (srow & 7)) * 8;
    int kbase = kc * 512;

    auto STAGE = [&](int p, int k0) {
        #pragma unroll
        for (int i = 0; i < 4; ++i)
            gload_lds16(A + (size_t)(m0 + i * 32 + srow) * CCH + k0 + scol, &At[p][i * 2048 + t * 8]);
        gload_lds16(B + (size_t)srow * CCH + k0 + scol, &Bt[p][t * 8]);
    };
    STAGE(0, kbase);
    __syncthreads();
    int cur = 0;
    for (int kt = 0; kt < 8; ++kt) {
        if (kt < 7) STAGE(cur ^ 1, kbase + (kt + 1) * 64);
        #pragma unroll
        for (int ks = 0; ks < 2; ++ks) {
            bf16x8 af[2], bf[2];
            #pragma unroll
            for (int fm = 0; fm < 2; ++fm)
                af[fm] = *(const bf16x8*)&At[cur][(wm + fm * 16 + l15) * 64 + offk[ks]];
            #pragma unroll
            for (int fn = 0; fn < 2; ++fn)
                bf[fn] = *(const bf16x8*)&Bt[cur][(fn * 16 + l15) * 64 + offk[ks]];
            #pragma unroll
            for (int fm = 0; fm < 2; ++fm)
                #pragma unroll
                for (int fn = 0; fn < 2; ++fn)
                    acc[fm][fn] = __builtin_amdgcn_mfma_f32_16x16x32_bf16(af[fm], bf[fn], acc[fm][fn], 0, 0, 0);
        }
        __syncthreads();
        cur ^= 1;
    }
    #pragma unroll
    for (int fm = 0; fm < 2; ++fm)
        #pragma unroll
        for (int fn = 0; fn < 2; ++fn)
            #pragma unroll
            for (int r = 0; r < 4; ++r) {
                int mg = m0 + wm + fm * 16 + lhi * 4 + r;
                int cg = fn * 16 + l15;
                P[kc * 65536 + mg * 32 + cg] = acc[fm][fn][r];
            }
}

// ---------- T reduce ----------
__global__ void k_t_reduce(const float* __restrict__ P, const float* __restrict__ bo,
                           float* __restrict__ Tm) {
    int idx0 = blockIdx.x * 1024 + threadIdx.x;
    #pragma unroll
    for (int k = 0; k < 4; ++k) {
        int idx = idx0 + k * 256;
        int q = idx >> 11, o = idx & 2047;
        float v = bo[o];
        #pragma unroll
        for (int kc = 0; kc < 4; ++kc) v += P[kc * 65536 + o * 32 + q];
        Tm[q * CCH + o] = v;
    }
}

// ---------- LN1 stats ----------
__global__ void k_ln1stat(const float* __restrict__ Tm, const float* __restrict__ x,
                          float* __restrict__ p1, float* __restrict__ p2) {
    int q = blockIdx.x, ch = blockIdx.y;
    int t = threadIdx.x;
    float sum = 0.f, ssq = 0.f;
    for (int j = 0; j < 32; ++j) {
        int i = ch * 8192 + j * 256 + t;
        float v = 16.f * Tm[q * CCH + (i >> 5)] + x[q * 65536 + i];
        sum += v; ssq += v * v;
    }
    #pragma unroll
    for (int off = 32; off > 0; off >>= 1) {
        sum += __shfl_down(sum, off);
        ssq += __shfl_down(ssq, off);
    }
    __shared__ float rs[4], rq[4];
    if ((t & 63) == 0) { rs[t >> 6] = sum; rq[t >> 6] = ssq; }
    __syncthreads();
    if (t == 0) {
        p1[q * 8 + ch] = rs[0] + rs[1] + rs[2] + rs[3];
        p2[q * 8 + ch] = rq[0] + rq[1] + rq[2] + rq[3];
    }
}

__global__ void k_lnfinish(const float* __restrict__ p1, const float* __restrict__ p2,
                           float* __restrict__ stats) {
    int q = blockIdx.x;
    if (threadIdx.x == 0) {
        float S = 0.f, Q = 0.f;
        for (int c = 0; c < 8; ++c) { S += p1[q * 8 + c]; Q += p2[q * 8 + c]; }
        float mu = S * (1.f / 65536.f);
        float var = Q * (1.f / 65536.f) - mu * mu;
        stats[q * 2] = mu;
        stats[q * 2 + 1] = rsqrtf(var + 1e-5f);
    }
}

// ---------- LN1 apply ----------
__global__ void k_ln1apply(const float* __restrict__ Tm, const float* __restrict__ x,
                           const float* __restrict__ stats,
                           const float* __restrict__ lnw, const float* __restrict__ lnb,
                           float* __restrict__ h1, u16* __restrict__ h1b) {
    int q = blockIdx.x, cb = blockIdx.y;
    int t = threadIdx.x;
    float mu = stats[q * 2], rstd = stats[q * 2 + 1];
    __shared__ u16 tile[32 * 132];
    for (int j = 0; j < 16; ++j) {
        int i = cb * 4096 + j * 256 + t;
        float v = 16.f * Tm[q * CCH + (i >> 5)] + x[q * 65536 + i];
        float g = (v - mu) * rstd * lnw[i] + lnb[i];
        h1[q * 65536 + i] = g;
        int cl = (j * 256 + t) >> 5;
        tile[(i & 31) * 132 + cl] = f2bf(g);
    }
    __syncthreads();
    for (int j = 0; j < 16; ++j) {
        int idx = j * 256 + t;
        int s = idx >> 7, cl = idx & 127;
        h1b[(size_t)(q * 32 + s) * CCH + cb * 128 + cl] = tile[s * 132 + cl];
    }
}

// ---------- MFMA GEMM split-K: P[kc][m][col] = sum_{k in chunk} A[m][k]*B[col][k] ----------
__global__ __launch_bounds__(256) void k_mfma_gemm_sk(
        const u16* __restrict__ A, const u16* __restrict__ B,
        float* __restrict__ P, int ldc) {
    int m0 = blockIdx.x * 128;
    int n0 = blockIdx.y * 64;
    int kc = blockIdx.z;
    int t = threadIdx.x;
    int lane = t & 63, wid = t >> 6;
    int wm = (wid >> 1) * 64, wn = (wid & 1) * 32;
    int l15 = lane & 15, lhi = lane >> 4, sw = l15 & 7;
    int offk[2] = { ((lhi) ^ sw) * 8, ((4 + lhi) ^ sw) * 8 };

    __shared__ u16 Atile[2][128 * 64];
    __shared__ u16 Btile[2][64 * 64];

    f32x4 z = {0.f, 0.f, 0.f, 0.f};
    f32x4 acc[4][2] = {{z, z}, {z, z}, {z, z}, {z, z}};

    int srow = t >> 3;
    int scol = ((t & 7) ^ (srow & 7)) * 8;   // pre-swizzled source chunk (rule #21)
    int kbase = kc * 1024;

    auto STAGE = [&](int p, int k0) {
        #pragma unroll
        for (int i = 0; i < 4; ++i)
            gload_lds16(A + (size_t)(m0 + i * 32 + srow) * CCH + k0 + scol,
                        &Atile[p][i * 2048 + t * 8]);
        #pragma unroll
        for (int i = 0; i < 2; ++i)
            gload_lds16(B + (size_t)(n0 + i * 32 + srow) * CCH + k0 + scol,
                        &Btile[p][i * 2048 + t * 8]);
    };

    STAGE(0, kbase);
    __syncthreads();
    int cur = 0;
    for (int kt = 0; kt < 16; ++kt) {
        if (kt < 15) STAGE(cur ^ 1, kbase + (kt + 1) * 64);
        #pragma unroll
        for (int ks = 0; ks < 2; ++ks) {
            bf16x8 af[4], bf[2];
            #pragma unroll
            for (int fm = 0; fm < 4; ++fm)
                af[fm] = *(const bf16x8*)&Atile[cur][(wm + fm * 16 + l15) * 64 + offk[ks]];
            #pragma unroll
            for (int fn = 0; fn < 2; ++fn)
                bf[fn] = *(const bf16x8*)&Btile[cur][(wn + fn * 16 + l15) * 64 + offk[ks]];
            #pragma unroll
            for (int fm = 0; fm < 4; ++fm)
                #pragma unroll
                for (int fn = 0; fn < 2; ++fn)
                    acc[fm][fn] = __builtin_amdgcn_mfma_f32_16x16x32_bf16(
                        af[fm], bf[fn], acc[fm][fn], 0, 0, 0);
        }
        __syncthreads();
        cur ^= 1;
    }

    #pragma unroll
    for (int fm = 0; fm < 4; ++fm)
        #pragma unroll
        for (int fn = 0; fn < 2; ++fn)
            #pragma unroll
            for (int r = 0; r < 4; ++r) {
                int mg = m0 + wm + fm * 16 + lhi * 4 + r;
                int cg = n0 + wn + fn * 16 + l15;
                P[(size_t)kc * 2097152 + (size_t)mg * ldc + cg] = acc[fm][fn][r];
            }
}

// ---------- G1 reduce: Y1b[tok][o] = bf16(relu(P0+P1)) ----------
__global__ void k_g1_reduce(const float* __restrict__ P, u16* __restrict__ Y1b) {
    int idx = (blockIdx.x * 256 + threadIdx.x) * 4;   // over 2M
    float4 a = *(const float4*)&P[idx];
    float4 b = *(const float4*)&P[2097152 + idx];
    u64 p = (u64)f2bf(fmaxf(a.x + b.x, 0.f))
          | ((u64)f2bf(fmaxf(a.y + b.y, 0.f)) << 16)
          | ((u64)f2bf(fmaxf(a.z + b.z, 0.f)) << 32)
          | ((u64)f2bf(fmaxf(a.w + b.w, 0.f)) << 48);
    *(u64*)&Y1b[idx] = p;
}

// ---------- G2 reduce: out[q][o][s] = P0[o][tok]+P1[o][tok]+h1[q][o][s] ----------
__global__ void k_g2_reduce(const float* __restrict__ P, const float* __restrict__ h1,
                            float* __restrict__ out) {
    int idx = (blockIdx.x * 256 + threadIdx.x) * 4;   // over 2M: o = idx>>10, tok = idx&1023
    int o = idx >> 10, tok = idx & 1023;
    int q = tok >> 5, s = tok & 31;
    size_t oaddr = (size_t)q * 65536 + (size_t)o * 32 + s;
    float4 a = *(const float4*)&P[idx];
    float4 b = *(const float4*)&P[2097152 + idx];
    float4 h = *(const float4*)&h1[oaddr];
    float4 v;
    v.x = a.x + b.x + h.x; v.y = a.y + b.y + h.y;
    v.z = a.z + b.z + h.z; v.w = a.w + b.w + h.w;
    *(float4*)&out[oaddr] = v;
}

// ---------- LN2 stats ----------
__global__ void k_ln2stat(const float* __restrict__ io,
                          float* __restrict__ p1, float* __restrict__ p2) {
    int q = blockIdx.x, ch = blockIdx.y;
    int t = threadIdx.x;
    float sum = 0.f, ssq = 0.f;
    for (int j = 0; j < 32; ++j) {
        float v = io[q * 65536 + ch * 8192 + j * 256 + t];
        sum += v; ssq += v * v;
    }
    #pragma unroll
    for (int off = 32; off > 0; off >>= 1) {
        sum += __shfl_down(sum, off);
        ssq += __shfl_down(ssq, off);
    }
    __shared__ float rs[4], rq[4];
    if ((t & 63) == 0) { rs[t >> 6] = sum; rq[t >> 6] = ssq; }
    __syncthreads();
    if (t == 0) {
        p1[q * 8 + ch] = rs[0] + rs[1] + rs[2] + rs[3];
        p2[q * 8 + ch] = rq[0] + rq[1] + rq[2] + rq[3];
    }
}

__global__ void k_ln2apply(float* __restrict__ io, const float* __restrict__ stats,
                           const float* __restrict__ lnw, const float* __restrict__ lnb) {
    int q = blockIdx.x, cb = blockIdx.y;
    int t = threadIdx.x;
    float mu = stats[q * 2], rstd = stats[q * 2 + 1];
    for (int j = 0; j < 16; ++j) {
        int i = cb * 4096 + j * 256 + t;
        float v = io[q * 65536 + i];
        io[q * 65536 + i] = (v - mu) * rstd * lnw[i] + lnb[i];
    }
}

extern "C" void kernel_launch(void* const* d_in, const int* in_sizes, int n_in,
                              void* d_out, int out_size, void* d_ws, size_t ws_size,
                              hipStream_t stream) {
    const float* x    = (const float*)d_in[0];
    const float* Wv   = (const float*)d_in[6];
    const float* bv   = (const float*)d_in[7];
    const float* Wo   = (const float*)d_in[8];
    const float* bo   = (const float*)d_in[9];
    const float* W1   = (const float*)d_in[10];
    const float* W2   = (const float*)d_in[11];
    const float* ln1w = (const float*)d_in[12];
    const float* ln1b = (const float*)d_in[13];
    const float* ln2w = (const float*)d_in[14];
    const float* ln2b = (const float*)d_in[15];
    float* out = (float*)d_out;

    float* ws    = (float*)d_ws;
    float* bvSum = ws;                    // 64
    float* stats = ws + 64;               // 64
    float* p1    = ws + 128;              // 256
    float* p2    = ws + 384;              // 256
    float* Psv   = ws + 640;              // 262144
    float* Pt    = ws + 262784;           // 262144
    float* Tm    = ws + 524928;           // 65536
    float* h1    = ws + 590464;           // 2097152
    float* Pg    = ws + 2687616;          // 4194304 (split-K partials, reused G1/G2)
    u16* ub      = (u16*)(ws + 6881920);
    u16* WvSumb  = ub;                    // 131072
    u16* xTb     = ub + 131072;           // 2097152
    u16* Svb     = ub + 2228224;          // 65536
    u16* h1b     = ub + 2293760;          // 2097152
    u16* Y1b     = ub + 4390912;          // 2097152
    u16* W1b     = ub + 6488064;          // 4194304
    u16* W2b     = ub + 10682368;         // 4194304
    u16* Wob     = ub + 14876672;         // 4194304  -> ~65.7 MB total

    k_convert3<<<12288, 256, 0, stream>>>(W1, W2, Wo, W1b, W2b, Wob);
    k_wvsum<<<512, 256, 0, stream>>>(Wv, bv, WvSumb, bvSum);
    k_xpose<<<dim3(32, 32), 256, 0, stream>>>(x, xTb);
    k_sv_gemm<<<dim3(16, 4), 256, 0, stream>>>(WvSumb, xTb, Psv);
    k_sv_reduce<<<64, 256, 0, stream>>>(Psv, bvSum, Svb);
    k_t_gemm<<<dim3(16, 4), 256, 0, stream>>>(Wob, Svb, Pt);
    k_t_reduce<<<64, 256, 0, stream>>>(Pt, bo, Tm);
    k_ln1stat<<<dim3(32, 8), 256, 0, stream>>>(Tm, x, p1, p2);
    k_lnfinish<<<32, 64, 0, stream>>>(p1, p2, stats);
    k_ln1apply<<<dim3(32, 16), 256, 0, stream>>>(Tm, x, stats, ln1w, ln1b, h1, h1b);
    // GEMM1: M=1024 (tokens) x N=2048 (o), split-K 2
    k_mfma_gemm_sk<<<dim3(8, 32, 2), 256, 0, stream>>>(h1b, W1b, Pg, 2048);
    k_g1_reduce<<<2048, 256, 0, stream>>>(Pg, Y1b);
    // GEMM2: M=2048 (o2) x N=1024 (tokens), split-K 2
    k_mfma_gemm_sk<<<dim3(16, 16, 2), 256, 0, stream>>>(W2b, Y1b, Pg, 1024);
    k_g2_reduce<<<2048, 256, 0, stream>>>(Pg, h1, out);
    k_ln2stat<<<dim3(32, 8), 256, 0, stream>>>(out, p1, p2);
    k_lnfinish<<<32, 64, 0, stream>>>(p1, p2, stats);
    k_ln2apply<<<dim3(32, 16), 256, 0, stream>>>(out, stats, ln2w, ln2b);
}

// Round 5
// 107.770 us; speedup vs baseline: 5.1278x; 1.0596x over previous
//
#include <hip/hip_runtime.h>

typedef unsigned short u16;
typedef unsigned int u32;
typedef unsigned long long u64;
typedef __attribute__((ext_vector_type(8))) short bf16x8;
typedef __attribute__((ext_vector_type(4))) float f32x4;

#define CCH 2048

__device__ __forceinline__ u16 f2bf(float f) {
    unsigned int x = __float_as_uint(f);
    unsigned int r = (x + 0x7fffu + ((x >> 16) & 1u)) >> 16;
    return (u16)r;
}

__device__ __forceinline__ void gload_lds16(const u16* g, u16* l) {
    __builtin_amdgcn_global_load_lds((const __attribute__((address_space(1))) void*)g,
                                     (__attribute__((address_space(3))) void*)l, 16, 0, 0);
}

// ---------- PREP: convert W1,W2,Wo -> bf16 | WvSum | x transpose ----------
__global__ void k_prep(const float* __restrict__ W1, const float* __restrict__ W2,
                       const float* __restrict__ Wo, const float* __restrict__ Wv,
                       const float* __restrict__ bv, const float* __restrict__ x,
                       u16* __restrict__ W1b, u16* __restrict__ W2b, u16* __restrict__ Wob,
                       u16* __restrict__ WvSumb, float* __restrict__ bvSum,
                       u16* __restrict__ xTb) {
    int b = blockIdx.x;
    int t = threadIdx.x;
    __shared__ float ftile[32][33];
    if (b < 12288) {
        // weight convert: 12288 blocks x 1024 elems
        long base = (long)b * 1024 + t * 4;
        const float* src; u16* dst; long off;
        if (base < 4194304)      { src = W1; dst = W1b; off = base; }
        else if (base < 8388608) { src = W2; dst = W2b; off = base - 4194304; }
        else                     { src = Wo; dst = Wob; off = base - 8388608; }
        float4 v = *(const float4*)&src[off];
        u64 p = (u64)f2bf(v.x) | ((u64)f2bf(v.y) << 16)
              | ((u64)f2bf(v.z) << 32) | ((u64)f2bf(v.w) << 48);
        *(u64*)&dst[off] = p;
    } else if (b < 12800) {
        // WvSum: 512 blocks
        int tt = (b - 12288) * 256 + t;
        int j = tt >> 11;
        float s = 0.f;
        #pragma unroll 8
        for (int m = 0; m < 32; ++m) s += Wv[(m * 64 + j) * CCH + (tt & 2047)];
        WvSumb[tt] = f2bf(s);
        if (tt < 64) {
            float bb = 0.f;
            for (int m = 0; m < 32; ++m) bb += bv[m * 64 + tt];
            bvSum[tt] = bb;
        }
    } else {
        // x transpose: 1024 blocks (cb, q)
        int bb = b - 12800;
        int cb = bb & 31, q = bb >> 5;
        int c0 = cb * 64;
        u32* xT32 = (u32*)xTb;
        #pragma unroll
        for (int half = 0; half < 2; ++half) {
            int ch = c0 + half * 32;
            #pragma unroll
            for (int k = 0; k < 4; ++k) {
                int i = t + k * 256;
                ftile[i & 31][i >> 5] = x[q * 65536 + (ch + (i >> 5)) * 32 + (i & 31)];
            }
            __syncthreads();
            #pragma unroll
            for (int k = 0; k < 2; ++k) {
                int i = t + k * 256;
                int s = i >> 4, cp = i & 15;
                u32 val = (u32)f2bf(ftile[s][cp * 2]) | ((u32)f2bf(ftile[s][cp * 2 + 1]) << 16);
                xT32[(size_t)(q * 32 + s) * 1024 + (ch >> 1) + cp] = val;
            }
            __syncthreads();
        }
    }
}

// ---------- Sv GEMM: P[kc][j][col] = sum_k WvSumb[j][k] * xTb[col][k] ----------
__global__ __launch_bounds__(256) void k_sv_gemm(const u16* __restrict__ A, const u16* __restrict__ B,
                                                 float* __restrict__ P) {
    int n0 = blockIdx.x * 64;
    int kc = blockIdx.y;
    int t = threadIdx.x;
    int lane = t & 63, wid = t >> 6;
    int wm = wid * 16;
    int l15 = lane & 15, lhi = lane >> 4, sw = l15 & 7;
    int offk[2] = { ((lhi) ^ sw) * 8, ((4 + lhi) ^ sw) * 8 };
    __shared__ u16 At[2][64 * 64];
    __shared__ u16 Bt[2][64 * 64];
    f32x4 z = {0.f, 0.f, 0.f, 0.f};
    f32x4 acc[4] = {z, z, z, z};
    int srow = t >> 3, scol = ((t & 7) ^ (srow & 7)) * 8;
    int kbase = kc * 512;

    auto STAGE = [&](int p, int k0) {
        #pragma unroll
        for (int i = 0; i < 2; ++i) {
            gload_lds16(A + (size_t)(i * 32 + srow) * CCH + k0 + scol, &At[p][i * 2048 + t * 8]);
            gload_lds16(B + (size_t)(n0 + i * 32 + srow) * CCH + k0 + scol, &Bt[p][i * 2048 + t * 8]);
        }
    };
    STAGE(0, kbase);
    __syncthreads();
    int cur = 0;
    for (int kt = 0; kt < 8; ++kt) {
        if (kt < 7) STAGE(cur ^ 1, kbase + (kt + 1) * 64);
        #pragma unroll
        for (int ks = 0; ks < 2; ++ks) {
            bf16x8 af = *(const bf16x8*)&At[cur][(wm + l15) * 64 + offk[ks]];
            #pragma unroll
            for (int fn = 0; fn < 4; ++fn) {
                bf16x8 bf = *(const bf16x8*)&Bt[cur][(fn * 16 + l15) * 64 + offk[ks]];
                acc[fn] = __builtin_amdgcn_mfma_f32_16x16x32_bf16(af, bf, acc[fn], 0, 0, 0);
            }
        }
        __syncthreads();
        cur ^= 1;
    }
    #pragma unroll
    for (int fn = 0; fn < 4; ++fn)
        #pragma unroll
        for (int r = 0; r < 4; ++r) {
            int j = wm + lhi * 4 + r;
            int col = n0 + fn * 16 + l15;
            P[kc * 65536 + j * 1024 + col] = acc[fn][r];
        }
}

// ---------- Sv reduce ----------
__global__ void k_sv_reduce(const float* __restrict__ P, const float* __restrict__ bvSum,
                            u16* __restrict__ Svb) {
    int idx0 = blockIdx.x * 1024 + threadIdx.x;
    #pragma unroll
    for (int k = 0; k < 4; ++k) {
        int idx = idx0 + k * 256;
        int j = idx >> 10, col = idx & 1023;
        float v = bvSum[j];
        #pragma unroll
        for (int kc = 0; kc < 4; ++kc) v += P[kc * 65536 + idx];
        Svb[(size_t)(col >> 5) * CCH + j * 32 + (col & 31)] = f2bf(v);
    }
}

// ---------- T GEMM: P[kc][o][q] = sum_k Wob[o][k] * Svb[q][k] ----------
__global__ __launch_bounds__(256) void k_t_gemm(const u16* __restrict__ A, const u16* __restrict__ B,
                                                float* __restrict__ P) {
    int m0 = blockIdx.x * 128;
    int kc = blockIdx.y;
    int t = threadIdx.x;
    int lane = t & 63, wid = t >> 6;
    int wm = wid * 32;
    int l15 = lane & 15, lhi = lane >> 4, sw = l15 & 7;
    int offk[2] = { ((lhi) ^ sw) * 8, ((4 + lhi) ^ sw) * 8 };
    __shared__ u16 At[2][128 * 64];
    __shared__ u16 Bt[2][32 * 64];
    f32x4 z = {0.f, 0.f, 0.f, 0.f};
    f32x4 acc[2][2] = {{z, z}, {z, z}};
    int srow = t >> 3, scol = ((t & 7) ^ (srow & 7)) * 8;
    int kbase = kc * 512;

    auto STAGE = [&](int p, int k0) {
        #pragma unroll
        for (int i = 0; i < 4; ++i)
            gload_lds16(A + (size_t)(m0 + i * 32 + srow) * CCH + k0 + scol, &At[p][i * 2048 + t * 8]);
        gload_lds16(B + (size_t)srow * CCH + k0 + scol, &Bt[p][t * 8]);
    };
    STAGE(0, kbase);
    __syncthreads();
    int cur = 0;
    for (int kt = 0; kt < 8; ++kt) {
        if (kt < 7) STAGE(cur ^ 1, kbase + (kt + 1) * 64);
        #pragma unroll
        for (int ks = 0; ks < 2; ++ks) {
            bf16x8 af[2], bf[2];
            #pragma unroll
            for (int fm = 0; fm < 2; ++fm)
                af[fm] = *(const bf16x8*)&At[cur][(wm + fm * 16 + l15) * 64 + offk[ks]];
            #pragma unroll
            for (int fn = 0; fn < 2; ++fn)
                bf[fn] = *(const bf16x8*)&Bt[cur][(fn * 16 + l15) * 64 + offk[ks]];
            #pragma unroll
            for (int fm = 0; fm < 2; ++fm)
                #pragma unroll
                for (int fn = 0; fn < 2; ++fn)
                    acc[fm][fn] = __builtin_amdgcn_mfma_f32_16x16x32_bf16(af[fm], bf[fn], acc[fm][fn], 0, 0, 0);
        }
        __syncthreads();
        cur ^= 1;
    }
    #pragma unroll
    for (int fm = 0; fm < 2; ++fm)
        #pragma unroll
        for (int fn = 0; fn < 2; ++fn)
            #pragma unroll
            for (int r = 0; r < 4; ++r) {
                int mg = m0 + wm + fm * 16 + lhi * 4 + r;
                int cg = fn * 16 + l15;
                P[kc * 65536 + mg * 32 + cg] = acc[fm][fn][r];
            }
}

// ---------- fused T reduce + LN1 stats: Tm[q][c] and partial (sum, ssq) of v=16T+x ----------
__global__ void k_t_reduce_ln1(const float* __restrict__ P, const float* __restrict__ bo,
                               const float* __restrict__ x, float* __restrict__ Tm,
                               float* __restrict__ p1, float* __restrict__ p2) {
    int q = blockIdx.x, ch = blockIdx.y;   // 32 x 8
    int t = threadIdx.x;                   // 256
    int c = ch * 256 + t;
    float T = bo[c];
    #pragma unroll
    for (int kc = 0; kc < 4; ++kc) T += P[kc * 65536 + c * 32 + q];
    Tm[q * CCH + c] = T;
    float T16 = 16.f * T;
    const float* xr = x + (size_t)q * 65536 + (size_t)c * 32;
    float sum = 0.f, ssq = 0.f;
    #pragma unroll
    for (int s4 = 0; s4 < 8; ++s4) {
        float4 xv = *(const float4*)&xr[s4 * 4];
        float v0 = T16 + xv.x, v1 = T16 + xv.y, v2 = T16 + xv.z, v3 = T16 + xv.w;
        sum += v0 + v1 + v2 + v3;
        ssq += v0 * v0 + v1 * v1 + v2 * v2 + v3 * v3;
    }
    #pragma unroll
    for (int off = 32; off > 0; off >>= 1) {
        sum += __shfl_down(sum, off);
        ssq += __shfl_down(ssq, off);
    }
    __shared__ float rs[4], rq[4];
    if ((t & 63) == 0) { rs[t >> 6] = sum; rq[t >> 6] = ssq; }
    __syncthreads();
    if (t == 0) {
        p1[q * 8 + ch] = rs[0] + rs[1] + rs[2] + rs[3];
        p2[q * 8 + ch] = rq[0] + rq[1] + rq[2] + rq[3];
    }
}

// ---------- LN1 apply (finish inline): h1 fp32 + h1b bf16 transposed ----------
__global__ void k_ln1apply(const float* __restrict__ Tm, const float* __restrict__ x,
                           const float* __restrict__ p1, const float* __restrict__ p2,
                           const float* __restrict__ lnw, const float* __restrict__ lnb,
                           float* __restrict__ h1, u16* __restrict__ h1b) {
    int q = blockIdx.x, cb = blockIdx.y;
    int t = threadIdx.x;
    float S = 0.f, Q = 0.f;
    #pragma unroll
    for (int cch = 0; cch < 8; ++cch) { S += p1[q * 8 + cch]; Q += p2[q * 8 + cch]; }
    float mu = S * (1.f / 65536.f);
    float rstd = rsqrtf(Q * (1.f / 65536.f) - mu * mu + 1e-5f);
    __shared__ u16 tile[32 * 132];
    for (int j = 0; j < 16; ++j) {
        int i = cb * 4096 + j * 256 + t;
        float v = 16.f * Tm[q * CCH + (i >> 5)] + x[q * 65536 + i];
        float g = (v - mu) * rstd * lnw[i] + lnb[i];
        h1[q * 65536 + i] = g;
        int cl = (j * 256 + t) >> 5;
        tile[(i & 31) * 132 + cl] = f2bf(g);
    }
    __syncthreads();
    for (int j = 0; j < 16; ++j) {
        int idx = j * 256 + t;
        int s = idx >> 7, cl = idx & 127;
        h1b[(size_t)(q * 32 + s) * CCH + cb * 128 + cl] = tile[s * 132 + cl];
    }
}

// ---------- MFMA GEMM split-K: P[kc][m][col] = sum_{k in chunk} A[m][k]*B[col][k] ----------
__global__ __launch_bounds__(256) void k_mfma_gemm_sk(
        const u16* __restrict__ A, const u16* __restrict__ B,
        float* __restrict__ P, int ldc) {
    int m0 = blockIdx.x * 128;
    int n0 = blockIdx.y * 64;
    int kc = blockIdx.z;
    int t = threadIdx.x;
    int lane = t & 63, wid = t >> 6;
    int wm = (wid >> 1) * 64, wn = (wid & 1) * 32;
    int l15 = lane & 15, lhi = lane >> 4, sw = l15 & 7;
    int offk[2] = { ((lhi) ^ sw) * 8, ((4 + lhi) ^ sw) * 8 };

    __shared__ u16 Atile[2][128 * 64];
    __shared__ u16 Btile[2][64 * 64];

    f32x4 z = {0.f, 0.f, 0.f, 0.f};
    f32x4 acc[4][2] = {{z, z}, {z, z}, {z, z}, {z, z}};

    int srow = t >> 3;
    int scol = ((t & 7) ^ (srow & 7)) * 8;
    int kbase = kc * 1024;

    auto STAGE = [&](int p, int k0) {
        #pragma unroll
        for (int i = 0; i < 4; ++i)
            gload_lds16(A + (size_t)(m0 + i * 32 + srow) * CCH + k0 + scol,
                        &Atile[p][i * 2048 + t * 8]);
        #pragma unroll
        for (int i = 0; i < 2; ++i)
            gload_lds16(B + (size_t)(n0 + i * 32 + srow) * CCH + k0 + scol,
                        &Btile[p][i * 2048 + t * 8]);
    };

    STAGE(0, kbase);
    __syncthreads();
    int cur = 0;
    for (int kt = 0; kt < 16; ++kt) {
        if (kt < 15) STAGE(cur ^ 1, kbase + (kt + 1) * 64);
        #pragma unroll
        for (int ks = 0; ks < 2; ++ks) {
            bf16x8 af[4], bf[2];
            #pragma unroll
            for (int fm = 0; fm < 4; ++fm)
                af[fm] = *(const bf16x8*)&Atile[cur][(wm + fm * 16 + l15) * 64 + offk[ks]];
            #pragma unroll
            for (int fn = 0; fn < 2; ++fn)
                bf[fn] = *(const bf16x8*)&Btile[cur][(wn + fn * 16 + l15) * 64 + offk[ks]];
            #pragma unroll
            for (int fm = 0; fm < 4; ++fm)
                #pragma unroll
                for (int fn = 0; fn < 2; ++fn)
                    acc[fm][fn] = __builtin_amdgcn_mfma_f32_16x16x32_bf16(
                        af[fm], bf[fn], acc[fm][fn], 0, 0, 0);
        }
        __syncthreads();
        cur ^= 1;
    }

    #pragma unroll
    for (int fm = 0; fm < 4; ++fm)
        #pragma unroll
        for (int fn = 0; fn < 2; ++fn)
            #pragma unroll
            for (int r = 0; r < 4; ++r) {
                int mg = m0 + wm + fm * 16 + lhi * 4 + r;
                int cg = n0 + wn + fn * 16 + l15;
                P[(size_t)kc * 2097152 + (size_t)mg * ldc + cg] = acc[fm][fn][r];
            }
}

// ---------- G1 reduce: Y1b[tok][o] = bf16(relu(P0+P1)) ----------
__global__ void k_g1_reduce(const float* __restrict__ P, u16* __restrict__ Y1b) {
    int idx = (blockIdx.x * 256 + threadIdx.x) * 4;
    float4 a = *(const float4*)&P[idx];
    float4 b = *(const float4*)&P[2097152 + idx];
    u64 p = (u64)f2bf(fmaxf(a.x + b.x, 0.f))
          | ((u64)f2bf(fmaxf(a.y + b.y, 0.f)) << 16)
          | ((u64)f2bf(fmaxf(a.z + b.z, 0.f)) << 32)
          | ((u64)f2bf(fmaxf(a.w + b.w, 0.f)) << 48);
    *(u64*)&Y1b[idx] = p;
}

// ---------- fused G2 reduce + residual + LN2 stats ----------
__global__ void k_g2_ln2(const float* __restrict__ P, const float* __restrict__ h1,
                         float* __restrict__ out, float* __restrict__ p1, float* __restrict__ p2) {
    int q = blockIdx.x, ch = blockIdx.y;   // 32 x 8
    int t = threadIdx.x;                   // 256
    int o = ch * 256 + t;
    const float* P0 = P + (size_t)o * 1024 + q * 32;
    const float* P1 = P + 2097152 + (size_t)o * 1024 + q * 32;
    const float* hr = h1 + (size_t)q * 65536 + (size_t)o * 32;
    float* orow = out + (size_t)q * 65536 + (size_t)o * 32;
    float sum = 0.f, ssq = 0.f;
    #pragma unroll
    for (int s4 = 0; s4 < 8; ++s4) {
        float4 a = *(const float4*)&P0[s4 * 4];
        float4 b = *(const float4*)&P1[s4 * 4];
        float4 h = *(const float4*)&hr[s4 * 4];
        float4 v;
        v.x = a.x + b.x + h.x; v.y = a.y + b.y + h.y;
        v.z = a.z + b.z + h.z; v.w = a.w + b.w + h.w;
        *(float4*)&orow[s4 * 4] = v;
        sum += v.x + v.y + v.z + v.w;
        ssq += v.x * v.x + v.y * v.y + v.z * v.z + v.w * v.w;
    }
    #pragma unroll
    for (int off = 32; off > 0; off >>= 1) {
        sum += __shfl_down(sum, off);
        ssq += __shfl_down(ssq, off);
    }
    __shared__ float rs[4], rq[4];
    if ((t & 63) == 0) { rs[t >> 6] = sum; rq[t >> 6] = ssq; }
    __syncthreads();
    if (t == 0) {
        p1[q * 8 + ch] = rs[0] + rs[1] + rs[2] + rs[3];
        p2[q * 8 + ch] = rq[0] + rq[1] + rq[2] + rq[3];
    }
}

// ---------- LN2 apply (finish inline), in-place on out ----------
__global__ void k_ln2apply(float* __restrict__ io, const float* __restrict__ p1,
                           const float* __restrict__ p2,
                           const float* __restrict__ lnw, const float* __restrict__ lnb) {
    int q = blockIdx.x, cb = blockIdx.y;
    int t = threadIdx.x;
    float S = 0.f, Q = 0.f;
    #pragma unroll
    for (int cch = 0; cch < 8; ++cch) { S += p1[q * 8 + cch]; Q += p2[q * 8 + cch]; }
    float mu = S * (1.f / 65536.f);
    float rstd = rsqrtf(Q * (1.f / 65536.f) - mu * mu + 1e-5f);
    for (int j = 0; j < 16; ++j) {
        int i = cb * 4096 + j * 256 + t;
        float v = io[q * 65536 + i];
        io[q * 65536 + i] = (v - mu) * rstd * lnw[i] + lnb[i];
    }
}

extern "C" void kernel_launch(void* const* d_in, const int* in_sizes, int n_in,
                              void* d_out, int out_size, void* d_ws, size_t ws_size,
                              hipStream_t stream) {
    const float* x    = (const float*)d_in[0];
    const float* Wv   = (const float*)d_in[6];
    const float* bv   = (const float*)d_in[7];
    const float* Wo   = (const float*)d_in[8];
    const float* bo   = (const float*)d_in[9];
    const float* W1   = (const float*)d_in[10];
    const float* W2   = (const float*)d_in[11];
    const float* ln1w = (const float*)d_in[12];
    const float* ln1b = (const float*)d_in[13];
    const float* ln2w = (const float*)d_in[14];
    const float* ln2b = (const float*)d_in[15];
    float* out = (float*)d_out;

    float* ws    = (float*)d_ws;
    float* bvSum = ws;                    // 64
    float* p1    = ws + 128;              // 256
    float* p2    = ws + 384;              // 256
    float* Psv   = ws + 640;              // 262144
    float* Pt    = ws + 262784;           // 262144
    float* Tm    = ws + 524928;           // 65536
    float* h1    = ws + 590464;           // 2097152
    float* Pg    = ws + 2687616;          // 4194304 (split-K partials)
    u16* ub      = (u16*)(ws + 6881920);
    u16* WvSumb  = ub;                    // 131072
    u16* xTb     = ub + 131072;           // 2097152
    u16* Svb     = ub + 2228224;          // 65536
    u16* h1b     = ub + 2293760;          // 2097152
    u16* Y1b     = ub + 4390912;          // 2097152
    u16* W1b     = ub + 6488064;          // 4194304
    u16* W2b     = ub + 10682368;         // 4194304
    u16* Wob     = ub + 14876672;         // 4194304

    k_prep<<<13824, 256, 0, stream>>>(W1, W2, Wo, Wv, bv, x, W1b, W2b, Wob, WvSumb, bvSum, xTb);
    k_sv_gemm<<<dim3(16, 4), 256, 0, stream>>>(WvSumb, xTb, Psv);
    k_sv_reduce<<<64, 256, 0, stream>>>(Psv, bvSum, Svb);
    k_t_gemm<<<dim3(16, 4), 256, 0, stream>>>(Wob, Svb, Pt);
    k_t_reduce_ln1<<<dim3(32, 8), 256, 0, stream>>>(Pt, bo, x, Tm, p1, p2);
    k_ln1apply<<<dim3(32, 16), 256, 0, stream>>>(Tm, x, p1, p2, ln1w, ln1b, h1, h1b);
    // GEMM1: M=1024 (tokens) x N=2048 (o), split-K 2
    k_mfma_gemm_sk<<<dim3(8, 32, 2), 256, 0, stream>>>(h1b, W1b, Pg, 2048);
    k_g1_reduce<<<2048, 256, 0, stream>>>(Pg, Y1b);
    // GEMM2: M=2048 (o) x N=1024 (tokens), split-K 2
    k_mfma_gemm_sk<<<dim3(16, 16, 2), 256, 0, stream>>>(W2b, Y1b, Pg, 1024);
    k_g2_ln2<<<dim3(32, 8), 256, 0, stream>>>(Pg, h1, out, p1, p2);
    k_ln2apply<<<dim3(32, 16), 256, 0, stream>>>(out, p1, p2, ln2w, ln2b);
}